// Round 14
// baseline (268.871 us; speedup 1.0000x reference)
//
#include <hip/hip_runtime.h>

#define B_SZ 4096
#define T_SZ 64
#define F_SZ 512
#define H_SZ 64
#define BR 8                    // 512 blocks, 2 blocks/CU
#define WIH_ELEMS (256 * 512)

typedef _Float16 f16x8 __attribute__((ext_vector_type(8)));
typedef float f32x4 __attribute__((ext_vector_type(4)));

__device__ __forceinline__ float fast_rcp(float x) { return __builtin_amdgcn_rcpf(x); }
__device__ __forceinline__ float sigm(float x) { return fast_rcp(1.0f + __expf(-x)); }
__device__ __forceinline__ float tanh_f(float x) {
  x = fminf(15.0f, fmaxf(-15.0f, x));
  float e = __expf(2.0f * x);
  return (e - 1.0f) * fast_rcp(e + 1.0f);
}
__device__ __forceinline__ f16x8 cvt8(float4 a, float4 b) {
  f16x8 h;
  h[0] = (_Float16)a.x; h[1] = (_Float16)a.y; h[2] = (_Float16)a.z; h[3] = (_Float16)a.w;
  h[4] = (_Float16)b.x; h[5] = (_Float16)b.y; h[6] = (_Float16)b.z; h[7] = (_Float16)b.w;
  return h;
}

__global__ void transcode_f16(const float* __restrict__ Wih, const float* __restrict__ Whh,
                              _Float16* __restrict__ ws) {
  const int i4 = (blockIdx.x * 256 + threadIdx.x) * 4;
  if (i4 < WIH_ELEMS) {
    float4 v = *(const float4*)(Wih + i4);
    ws[i4] = (_Float16)v.x; ws[i4+1] = (_Float16)v.y; ws[i4+2] = (_Float16)v.z; ws[i4+3] = (_Float16)v.w;
  } else {
    const int j4 = i4 - WIH_ELEMS;
    float4 v = *(const float4*)(Whh + j4);
    _Float16* w2 = ws + WIH_ELEMS;
    w2[j4] = (_Float16)v.x; w2[j4+1] = (_Float16)v.y; w2[j4+2] = (_Float16)v.z; w2[j4+3] = (_Float16)v.w;
  }
}

// untracked 16B load with literal offset (string)
#define GLD(dst, ptr, OFF) \
  asm volatile("global_load_dwordx4 %0, %1, off offset:" OFF : "=v"(dst) : "v"(ptr) : "memory")
#define LOADB(BUF, O0, O1) do {                               \
    GLD(BUF[0][0], wB[0], O0); GLD(BUF[0][1], wB[0], O1);     \
    GLD(BUF[1][0], wB[1], O0); GLD(BUF[1][1], wB[1], O1);     \
    GLD(BUF[2][0], wB[2], O0); GLD(BUF[2][1], wB[2], O1);     \
    GLD(BUF[3][0], wB[3], O0); GLD(BUF[3][1], wB[3], O1);     \
  } while (0)

// Fused LSTM. TC=4 chunks (16 chunks x 8 k-tiles = 128 iters). Per wave per iter exactly
// 10 VMEM: 8 asm B-loads (untracked) + 2 global_load_lds (8KB tile into ring-4, issued
// 3 iters ahead, order B-before-DMA). Hand-placed vmcnt(12) retires exactly
// {DMA(tau+1), B(tau)} -- both >=1 iter old -- keeping DMA(tau+2)+DMA(tau+3) (16KB/block)
// permanently in flight. Dual accumulators: aG = current chunk's xg GEMM; aS = previous
// chunk's gates, consumed by merged scan steps (2 per odd iter pair) directly from
// registers (no xgb LDS, no handoff barrier). No compiler-tracked VMEM in the loop.
__global__ __launch_bounds__(256, 2)
void lstm_fused(const float* __restrict__ x, const _Float16* __restrict__ ws,
                const float* __restrict__ bih, const float* __restrict__ bhh,
                const float* __restrict__ Wfc, const float* __restrict__ bfc,
                float* __restrict__ out)
{
  __shared__ __align__(16) float Ax[4][32 * 64];   // ring-4 x 8KB fp32 tiles
  __shared__ __align__(16) _Float16 hbuf[2][8][72];
  __shared__ float cb[8][64];
  __shared__ float h32[8][64];

  const int tid  = threadIdx.x;
  const int wv   = tid >> 6;
  const int lane = tid & 63;
  const int ln   = lane & 15;
  const int kg   = lane >> 4;
  const int br0  = blockIdx.x * BR;
  const int u    = wv * 16 + ln;

  const _Float16* Wihh = ws;
  const _Float16* Whhh = ws + WIH_ELEMS;

  for (int i = tid; i < 2 * 8 * 72; i += 256) (&hbuf[0][0][0])[i] = (_Float16)0.0f;
  for (int i = tid; i < 8 * 64; i += 256) (&cb[0][0])[i] = 0.0f;

  // Whh fragments + bias (tracked loads; retired in prologue)
  f16x8 whhf[4][2];
  #pragma unroll
  for (int g = 0; g < 4; ++g)
    #pragma unroll
    for (int k2 = 0; k2 < 2; ++k2)
      whhf[g][k2] = *(const f16x8*)(Whhh + (size_t)((g * 4 + wv) * 16 + ln) * H_SZ
                                         + kg * 8 + k2 * 32);
  float bsum[4];
  #pragma unroll
  for (int g = 0; g < 4; ++g) bsum[g] = bih[g * 64 + u] + bhh[g * 64 + u];  // add forces wait
  __syncthreads();
  #pragma unroll
  for (int g = 0; g < 4; ++g)   // force whhf materialization NOW (no tracked wait in loop)
    asm volatile("" : "+v"(whhf[g][0]), "+v"(whhf[g][1]));

  // B gate base pointers (offset immediates select kq)
  const _Float16* wB[4];
  #pragma unroll
  for (int g = 0; g < 4; ++g)
    wB[g] = Wihh + (size_t)((g * 4 + wv) * 16 + ln) * F_SZ + kg * 8;

  // DMA one 8KB tile (2 instr/wave x 1KB). m = i*4+(l>>4): t_local=m>>3, b=m&7.
  // LDS dest linear (chunk l&15); source chunk pre-swizzled: (l&15)^(m&7).
  auto issueD = [&](int t2, int slotLit) {
    const int tt = t2 < 128 ? t2 : 127;          // tail dummies keep counts uniform
    const int c2 = tt >> 3, kq = tt & 7;
    #pragma unroll
    for (int j = 0; j < 2; ++j) {
      const int i  = wv * 2 + j;
      const int m  = i * 4 + (lane >> 4);
      const int sc = (lane & 15) ^ (m & 7);
      const float* gp = x + (size_t)(br0 + (m & 7)) * (T_SZ * F_SZ)
                          + (size_t)(c2 * 4 + (m >> 3)) * F_SZ + kq * 64 + sc * 4;
      __builtin_amdgcn_global_load_lds(gp, &Ax[slotLit][i * 256], 16, 0, 0);
    }
  };

  f32x4 aG[2][4], aS[2][4];
  f16x8 bfA[4][2], bfB[4][2];
  #pragma unroll
  for (int mt = 0; mt < 2; ++mt)
    #pragma unroll
    for (int g = 0; g < 4; ++g) aG[mt][g] = (f32x4){0.0f, 0.0f, 0.0f, 0.0f};

  auto consume = [&](const f16x8 (&B)[4][2], const int slotLit) {
    const float* ab = &Ax[slotLit][0];
    #pragma unroll
    for (int ks = 0; ks < 2; ++ks)
      #pragma unroll
      for (int mt = 0; mt < 2; ++mt) {
        const int row = mt * 16 + ln;
        const int p0  = (ks * 8 + kg * 2) ^ (ln & 7);
        float4 a0 = *(const float4*)(ab + row * 64 + p0 * 4);
        float4 a1 = *(const float4*)(ab + row * 64 + (p0 ^ 1) * 4);
        f16x8 af = cvt8(a0, a1);
        #pragma unroll
        for (int g = 0; g < 4; ++g)
          aG[mt][g] = __builtin_amdgcn_mfma_f32_16x16x32_f16(af, B[g][ks], aG[mt][g], 0, 0, 0);
      }
  };

  // One scan step: gates = cRow (AGPR, previous chunk) + h@Whh^T; step half is literal.
  auto scanStep = [&](const f32x4 (&cRow)[4], const int half, const bool wH) {
    f16x8 ah0 = (f16x8){0, 0, 0, 0, 0, 0, 0, 0};
    f16x8 ah1 = (f16x8){0, 0, 0, 0, 0, 0, 0, 0};
    if ((ln >> 3) == half) {
      const _Float16* hr = &hbuf[half][ln & 7][0];
      ah0 = *(const f16x8*)(hr + kg * 8);
      ah1 = *(const f16x8*)(hr + kg * 8 + 32);
    }
    f32x4 gf[4];
    #pragma unroll
    for (int g = 0; g < 4; ++g) {
      gf[g] = __builtin_amdgcn_mfma_f32_16x16x32_f16(ah0, whhf[g][0], cRow[g], 0, 0, 0);
      gf[g] = __builtin_amdgcn_mfma_f32_16x16x32_f16(ah1, whhf[g][1], gf[g], 0, 0, 0);
    }
    if ((kg >> 1) == half) {
      const int b0 = (kg & 1) * 4;
      #pragma unroll
      for (int r = 0; r < 4; ++r) {
        const float iv = sigm(gf[0][r] + bsum[0]);
        const float fv = sigm(gf[1][r] + bsum[1]);
        const float gv = tanh_f(gf[2][r] + bsum[2]);
        const float ov = sigm(gf[3][r] + bsum[3]);
        const float cn = fv * cb[b0 + r][u] + iv * gv;
        cb[b0 + r][u] = cn;
        const float hn = ov * tanh_f(cn);
        hbuf[half ^ 1][b0 + r][u] = (_Float16)hn;
        if (wH) h32[b0 + r][u] = hn;
      }
    }
  };

// Iter body (KK literal). Consumes CBUF=B(kk)+tile; loads LBUF=B(kk+1); issues D(+3).
#define BODY(KK, ONX0, ONX1, CBUF, LBUF)                                        \
  do {                                                                          \
    LOADB(LBUF, ONX0, ONX1);                                                    \
    issueD(cc * 8 + KK + 3, (KK + 3) & 3);                                      \
    __builtin_amdgcn_sched_barrier(0);                                          \
    asm volatile("s_waitcnt vmcnt(12)" ::: "memory");                           \
    __builtin_amdgcn_sched_barrier(0);                                          \
    consume(CBUF, KK & 3);                                                      \
    if ((KK & 1) && cc > 0) scanStep(aS[(KK >> 1) >> 1], (KK >> 1) & 1, false); \
    asm volatile("s_waitcnt lgkmcnt(0)" ::: "memory");                          \
    __builtin_amdgcn_s_barrier();                                               \
    __builtin_amdgcn_sched_barrier(0);                                          \
  } while (0)

  // Prologue: invariant queue [D(1):2, B(0):8, D(2):2] after retiring D(0).
  issueD(0, 0);
  issueD(1, 1);
  LOADB(bfA, "0", "64");
  issueD(2, 2);
  __builtin_amdgcn_sched_barrier(0);
  asm volatile("s_waitcnt vmcnt(12)" ::: "memory");
  __builtin_amdgcn_s_barrier();
  __builtin_amdgcn_sched_barrier(0);

  for (int cc = 0; cc < 16; ++cc) {
    BODY(0, "128", "192", bfA, bfB);
    BODY(1, "256", "320", bfB, bfA);
    BODY(2, "384", "448", bfA, bfB);
    BODY(3, "512", "576", bfB, bfA);
    BODY(4, "640", "704", bfA, bfB);
    BODY(5, "768", "832", bfB, bfA);
    BODY(6, "896", "960", bfA, bfB);
    BODY(7, "0",   "64",  bfB, bfA);
    // chunk end: gates -> aS (registers, per-lane; no barrier needed), reset aG
    #pragma unroll
    for (int mt = 0; mt < 2; ++mt)
      #pragma unroll
      for (int g = 0; g < 4; ++g) {
        aS[mt][g] = aG[mt][g];
        aG[mt][g] = (f32x4){0.0f, 0.0f, 0.0f, 0.0f};
      }
  }
#undef BODY

  // Epilogue: last chunk's 4 scan steps (sigma 60..63).
  scanStep(aS[0], 0, false);
  asm volatile("s_waitcnt lgkmcnt(0)" ::: "memory");
  __builtin_amdgcn_s_barrier();
  scanStep(aS[0], 1, false);
  asm volatile("s_waitcnt lgkmcnt(0)" ::: "memory");
  __builtin_amdgcn_s_barrier();
  scanStep(aS[1], 0, false);
  asm volatile("s_waitcnt lgkmcnt(0)" ::: "memory");
  __builtin_amdgcn_s_barrier();
  scanStep(aS[1], 1, true);

  __syncthreads();   // drains tail dummy DMAs, h32 visible
  if (tid < 16) {
    const int r = tid >> 1, j = tid & 1;
    float a = bfc[j];
    #pragma unroll
    for (int uu = 0; uu < 64; ++uu) a += h32[r][uu] * Wfc[j * 64 + uu];
    out[(size_t)(br0 + r) * 2 + j] = a;
  }
}

extern "C" void kernel_launch(void* const* d_in, const int* in_sizes, int n_in,
                              void* d_out, int out_size, void* d_ws, size_t ws_size,
                              hipStream_t stream) {
  const float* x   = (const float*)d_in[0];
  const float* Wih = (const float*)d_in[1];
  const float* Whh = (const float*)d_in[2];
  const float* bih = (const float*)d_in[3];
  const float* bhh = (const float*)d_in[4];
  const float* Wfc = (const float*)d_in[5];
  const float* bfc = (const float*)d_in[6];
  float* out = (float*)d_out;
  _Float16* ws = (_Float16*)d_ws;   // 272 KB used

  transcode_f16<<<dim3(144), dim3(256), 0, stream>>>(Wih, Whh, ws);
  lstm_fused<<<dim3(B_SZ / BR), dim3(256), 0, stream>>>(x, ws, bih, bhh, Wfc, bfc, out);
}